// Round 12
// baseline (181.778 us; speedup 1.0000x reference)
//
#include <hip/hip_runtime.h>
#include <hip/hip_bf16.h>

typedef __hip_bfloat16 bf16_t;
typedef __bf16 bf16x8 __attribute__((ext_vector_type(8)));      // 16x16x32 A/B frag
typedef __bf16 bf16x4 __attribute__((ext_vector_type(4)));      // 16x16x16 A/B frag
typedef short  s16x4  __attribute__((ext_vector_type(4)));
typedef float  f32x4  __attribute__((ext_vector_type(4)));      // C/D frag

#define MFMA(a, b, c) __builtin_amdgcn_mfma_f32_16x16x32_bf16((a), (b), (c), 0, 0, 0)

__device__ __forceinline__ f32x4 mfma16(bf16x4 a, bf16x4 b, f32x4 c) {
#if __has_builtin(__builtin_amdgcn_mfma_f32_16x16x16_bf16)
  return __builtin_amdgcn_mfma_f32_16x16x16_bf16(a, b, c, 0, 0, 0);
#else
  return __builtin_amdgcn_mfma_f32_16x16x16bf16_1k(
      __builtin_bit_cast(s16x4, a), __builtin_bit_cast(s16x4, b), c, 0, 0, 0);
#endif
}

// Raw v_exp_f32: skips ocml's denorm-range fixup (~4 extra VALU/exp).
__device__ __forceinline__ float fast_exp2(float x) {
#if __has_builtin(__builtin_amdgcn_exp2f)
  return __builtin_amdgcn_exp2f(x);
#else
  float r;
  asm("v_exp_f32 %0, %1" : "=v"(r) : "v"(x));
  return r;
#endif
}

__device__ __forceinline__ bf16x8 ldg8(const bf16_t* p) {
  return *reinterpret_cast<const bf16x8*>(p);
}
__device__ __forceinline__ bf16x4 ldg4(const bf16_t* p) {
  return *reinterpret_cast<const bf16x4*>(p);
}
__device__ __forceinline__ void st8(bf16_t* p, bf16x8 v) {
  *reinterpret_cast<bf16x8*>(p) = v;
}
__device__ __forceinline__ void store_out(bf16_t* p, float v) { *p = __float2bfloat16(v); }
__device__ __forceinline__ void store_out(float* p, float v)  { *p = v; }

// async global->LDS, 16B per lane. LDS dest is wave-uniform base + lane*16.
__device__ __forceinline__ void async16(const bf16_t* g, bf16_t* l) {
  __builtin_amdgcn_global_load_lds(
      (const __attribute__((address_space(1))) void*)g,
      (__attribute__((address_space(3))) void*)l, 16, 0, 0);
}

// ---------------------------------------------------------------------------
// f32 -> bf16 conversion; folds softmax scale (1/8 * log2e) into Wq.
// ---------------------------------------------------------------------------
__global__ __launch_bounds__(256) void cvt_kernel(
    const float* __restrict__ x,  const float* __restrict__ Wq,
    const float* __restrict__ Wk, const float* __restrict__ Wv,
    const float* __restrict__ Wo,
    bf16_t* __restrict__ xb,  bf16_t* __restrict__ Wqb,
    bf16_t* __restrict__ Wkb, bf16_t* __restrict__ Wvb,
    bf16_t* __restrict__ Wob) {
  const int bid = blockIdx.x;
  const float* src; bf16_t* dst; size_t base;
  float scl = 1.0f;
  if (bid < 2048)      { src = x;  dst = xb;  base = (size_t)bid * 2048; }
  else if (bid < 2560) { src = Wq; dst = Wqb; base = (size_t)(bid - 2048) * 2048;
                         scl = 0.180336878f; }  // 0.125 * log2(e)
  else if (bid < 3072) { src = Wk; dst = Wkb; base = (size_t)(bid - 2560) * 2048; }
  else if (bid < 3584) { src = Wv; dst = Wvb; base = (size_t)(bid - 3072) * 2048; }
  else                 { src = Wo; dst = Wob; base = (size_t)(bid - 3584) * 2048; }
  const size_t i0 = base + (size_t)threadIdx.x * 8;
  const float4 f0 = *reinterpret_cast<const float4*>(src + i0);
  const float4 f1 = *reinterpret_cast<const float4*>(src + i0 + 4);
  bf16x8 v;
  v[0] = (__bf16)(f0.x * scl); v[1] = (__bf16)(f0.y * scl);
  v[2] = (__bf16)(f0.z * scl); v[3] = (__bf16)(f0.w * scl);
  v[4] = (__bf16)(f1.x * scl); v[5] = (__bf16)(f1.y * scl);
  v[6] = (__bf16)(f1.z * scl); v[7] = (__bf16)(f1.w * scl);
  st8(dst + i0, v);
}

// ---------------------------------------------------------------------------
// GEMM tile (round-2/10 verified structure): C[128x128]=A[128xK]*B[128xK]^T,
// K=1024, BK=64, global_load_lds width-16 staging with XOR-chunk swizzle.
// [R8 dbuf BK=32: hurt (+4.7us). R11 counted-vmcnt 3-buffer: hurt (+4.7us)
// — T4 requires the 8-phase interleave regime (guide m218/m230); on a
// 2-barrier-per-step structure it is null-to-negative, and doubling the
// barrier count + sched_barrier(0) pinning (m141) cost more than the
// counted waits saved. This m97-style structure is the measured best.]
// ---------------------------------------------------------------------------
#define GK 1024

template <typename OutT, bool BIAS>
__device__ __forceinline__ void gemm_tile(
    const bf16_t* __restrict__ A, const bf16_t* __restrict__ B,
    OutT* __restrict__ C, const float* __restrict__ bias,
    int bm, int bn, int ldc, bf16_t* As, bf16_t* Bs) {
  const int tid  = threadIdx.x;
  const int lane = tid & 63;
  const int wave = tid >> 6;
  const int wm   = (wave & 1) << 6;
  const int wn   = (wave >> 1) << 6;
  const int lr   = lane & 15;
  const int lq   = lane >> 4;

  const int srow = tid >> 3;                        // 0..31
  const int sx   = ((tid & 7) ^ (srow & 7)) << 3;   // swizzled source offset

  const bf16_t* Ag = A + (size_t)(bm + srow) * GK + sx;
  const bf16_t* Bg = B + (size_t)(bn + srow) * GK + sx;
  bf16_t* Asw = As + wave * 512;
  bf16_t* Bsw = Bs + wave * 512;

  f32x4 acc[4][4];
#pragma unroll
  for (int i = 0; i < 4; ++i)
#pragma unroll
    for (int j = 0; j < 4; ++j) acc[i][j] = (f32x4){0.f, 0.f, 0.f, 0.f};

  for (int k0 = 0; k0 < GK; k0 += 64) {
    __syncthreads();
#pragma unroll
    for (int g = 0; g < 4; ++g) {
      async16(Ag + k0 + (size_t)(g * 32) * GK, Asw + g * 2048);
      async16(Bg + k0 + (size_t)(g * 32) * GK, Bsw + g * 2048);
    }
    __syncthreads();
#pragma unroll
    for (int ks = 0; ks < 2; ++ks) {
      bf16x8 af[4], bf[4];
      const int chs = ((ks * 4 + lq) ^ (lr & 7)) << 3;
#pragma unroll
      for (int i = 0; i < 4; ++i) {
        af[i] = ldg8(&As[(wm + i * 16 + lr) * 64 + chs]);
        bf[i] = ldg8(&Bs[(wn + i * 16 + lr) * 64 + chs]);
      }
#pragma unroll
      for (int mi = 0; mi < 4; ++mi)
#pragma unroll
        for (int ni = 0; ni < 4; ++ni)
          acc[mi][ni] = MFMA(af[mi], bf[ni], acc[mi][ni]);
    }
  }

  // C/D layout: col = lane&15, row = (lane>>4)*4 + r  (m89-verified)
#pragma unroll
  for (int ni = 0; ni < 4; ++ni) {
    const int col = bn + wn + ni * 16 + lr;
    float bv = 0.f;
    if (BIAS) bv = bias[col];
#pragma unroll
    for (int mi = 0; mi < 4; ++mi) {
#pragma unroll
      for (int r = 0; r < 4; ++r) {
        const int row = bm + wm + mi * 16 + lq * 4 + r;
        store_out(&C[(size_t)row * ldc + col], acc[mi][ni][r] + bv);
      }
    }
  }
}

// ---------------------------------------------------------------------------
// GEMM tile 128x64 (out_proj, round-10 verified): out_proj at 256 blocks was
// 1 block/CU; N-split to 64 cols doubles the grid to 512 (2/CU). -7us.
// ---------------------------------------------------------------------------
template <typename OutT, bool BIAS>
__device__ __forceinline__ void gemm_tile_n64(
    const bf16_t* __restrict__ A, const bf16_t* __restrict__ B,
    OutT* __restrict__ C, const float* __restrict__ bias,
    int bm, int bn, int ldc, bf16_t* As, bf16_t* Bs) {
  const int tid  = threadIdx.x;
  const int lane = tid & 63;
  const int wave = tid >> 6;
  const int wm   = (wave & 1) << 6;    // 0/64
  const int wn   = (wave >> 1) << 5;   // 0/32
  const int lr   = lane & 15;
  const int lq   = lane >> 4;

  const int srow = tid >> 3;                        // 0..31
  const int sx   = ((tid & 7) ^ (srow & 7)) << 3;   // swizzled source offset

  const bf16_t* Ag = A + (size_t)(bm + srow) * GK + sx;
  const bf16_t* Bg = B + (size_t)(bn + srow) * GK + sx;
  bf16_t* Asw = As + wave * 512;
  bf16_t* Bsw = Bs + wave * 512;

  f32x4 acc[4][2];
#pragma unroll
  for (int i = 0; i < 4; ++i)
#pragma unroll
    for (int j = 0; j < 2; ++j) acc[i][j] = (f32x4){0.f, 0.f, 0.f, 0.f};

  for (int k0 = 0; k0 < GK; k0 += 64) {
    __syncthreads();
#pragma unroll
    for (int g = 0; g < 4; ++g)
      async16(Ag + k0 + (size_t)(g * 32) * GK, Asw + g * 2048);
#pragma unroll
    for (int g = 0; g < 2; ++g)
      async16(Bg + k0 + (size_t)(g * 32) * GK, Bsw + g * 2048);
    __syncthreads();
#pragma unroll
    for (int ks = 0; ks < 2; ++ks) {
      bf16x8 af[4], bf[2];
      const int chs = ((ks * 4 + lq) ^ (lr & 7)) << 3;
#pragma unroll
      for (int i = 0; i < 4; ++i)
        af[i] = ldg8(&As[(wm + i * 16 + lr) * 64 + chs]);
#pragma unroll
      for (int i = 0; i < 2; ++i)
        bf[i] = ldg8(&Bs[(wn + i * 16 + lr) * 64 + chs]);
#pragma unroll
      for (int mi = 0; mi < 4; ++mi)
#pragma unroll
        for (int ni = 0; ni < 2; ++ni)
          acc[mi][ni] = MFMA(af[mi], bf[ni], acc[mi][ni]);
    }
  }

#pragma unroll
  for (int ni = 0; ni < 2; ++ni) {
    const int col = bn + wn + ni * 16 + lr;
    float bv = 0.f;
    if (BIAS) bv = bias[col];
#pragma unroll
    for (int mi = 0; mi < 4; ++mi) {
#pragma unroll
      for (int r = 0; r < 4; ++r) {
        const int row = bm + wm + mi * 16 + lq * 4 + r;
        store_out(&C[(size_t)row * ldc + col], acc[mi][ni][r] + bv);
      }
    }
  }
}

// XCD-aware remap: same-x-tile blocks share bid%8 -> same XCD L2.
// z=0: Q = x Wq^T;  z=1: K = x Wk^T;  z=2: Vt = Wv x^T [1024x4096]
__global__ __launch_bounds__(256) void qkv_kernel(
    const bf16_t* __restrict__ x, const bf16_t* __restrict__ Wq,
    const bf16_t* __restrict__ Wk, const bf16_t* __restrict__ Wv,
    bf16_t* __restrict__ Q, bf16_t* __restrict__ Kp, bf16_t* __restrict__ Vt) {
  __shared__ alignas(16) bf16_t As[128 * 64];
  __shared__ alignas(16) bf16_t Bs[128 * 64];
  const int bid = blockIdx.x;
  const int z   = blockIdx.y;
  const int mt  = (bid & 31) * 128;   // x token-tile; XCD = bid%8 = mt-tile%8
  const int nt  = (bid >> 5) * 128;
  if (z == 0) {
    gemm_tile<bf16_t, false>(x, Wq, Q, nullptr, mt, nt, 1024, As, Bs);
  } else if (z == 1) {
    gemm_tile<bf16_t, false>(x, Wk, Kp, nullptr, mt, nt, 1024, As, Bs);
  } else {
    gemm_tile<bf16_t, false>(Wv, x, Vt, nullptr, nt, mt, 4096, As, Bs);
  }
}

__global__ __launch_bounds__(256) void out_proj_kernel(
    const bf16_t* __restrict__ Ao, const bf16_t* __restrict__ Wo,
    const float* __restrict__ bias, float* __restrict__ out) {
  __shared__ alignas(16) bf16_t As[128 * 64];
  __shared__ alignas(16) bf16_t Bs[64 * 64];
  const int bid = blockIdx.x;
  gemm_tile_n64<float, true>(Ao, Wo, out, bias, (bid & 31) * 128,
                             (bid >> 5) * 64, 1024, As, Bs);
}

// ---------------------------------------------------------------------------
// Attention, round 12: round-10 verified structure (8 waves x 16 q-rows,
// KVBLK=128, dbuf K/V, register P, raw-exp softmax; 52.5us, MfmaUtil 39,
// VALU 42) + T5 s_setprio around the MFMA clusters. Waves drift apart
// within the 8 unrolled c-iterations (no intra-tile sync), so at any time
// some waves are in MFMA phase and some in exp/VALU phase -> setprio(1)
// on the MFMA clusters lets MFMA-phase waves win CU issue arbitration
// (m191: +4-7% attn; m190: null only for lockstep structures).
// ---------------------------------------------------------------------------
#define VPADA 132

__global__ __launch_bounds__(512, 4) void attn_kernel(
    const bf16_t* __restrict__ Q, const bf16_t* __restrict__ Kp,
    const bf16_t* __restrict__ Vt, bf16_t* __restrict__ Ao) {
  // Ks0|Ks1: [128 kv][64 hd] swizzled (16384 B each)
  // Vs0|Vs1: [64 hd][VPADA kv] (16896 B each).  Osc overlay: 34816 B.
  __shared__ alignas(16) char smem_raw[2 * 16384 + 2 * 16896];  // 66560 B
  bf16_t* Ks0 = (bf16_t*)smem_raw;
  bf16_t* Ks1 = Ks0 + 8192;
  bf16_t* Vs0 = (bf16_t*)(smem_raw + 32768);
  bf16_t* Vs1 = Vs0 + 64 * VPADA;
  float*  Osc = (float*)smem_raw;                  // epilogue scratch

  const int tid  = threadIdx.x;                    // 0..511
  const int lane = tid & 63;
  const int wave = tid >> 6;                       // 0..7
  const int lr   = lane & 15;
  const int lq   = lane >> 4;
  const int bh   = blockIdx.x;
  const int qt   = blockIdx.y;
  const int b    = bh >> 4;
  const int h    = bh & 15;
  const size_t tok0 = (size_t)b * 2048;
  const int col0 = h * 64;
  const int qblk = qt * 128 + wave * 16;           // wave's 16 q-rows

  // Q B-frags (n = q = lane&15, k = hd = c*32 + lq*8 + i), held in regs
  bf16x8 qf[2];
  {
    const size_t qrow = tok0 + qblk + lr;
#pragma unroll
    for (int c = 0; c < 2; ++c)
      qf[c] = ldg8(&Q[qrow * 1024 + col0 + c * 32 + lq * 8]);
  }

  f32x4 o[4];  // O^T accum: D[m=hd=ht*16+lq*4+r][n=q=lr]
#pragma unroll
  for (int i = 0; i < 4; ++i) o[i] = (f32x4){0.f, 0.f, 0.f, 0.f};
  float lsum = 0.f;

  // staging: K rows srow, srow+64 (same parity -> same swizzle); V rows
  // srow (hd), kv chunks sxv and sxv+64.
  const int srow = tid >> 3;                       // 0..63
  const int sxk  = ((tid & 7) ^ (srow & 7)) << 3;  // K swizzled source chunk
  const int sxv  = (tid & 7) << 3;
  const int kdst = wave * 512;                     // wave-uniform LDS elems

  // frag-read LDS offsets (elems)
  const int koff0 = lr * 64 + ((lq ^ (lr & 7)) << 3);
  const int koff1 = lr * 64 + (((lq + 4) ^ (lr & 7)) << 3);
  const int voff  = lr * VPADA + lq * 4;

  const bf16_t* Kg0 = Kp + tok0 * 1024 + col0;
  const bf16_t* Vg0 = Vt + (size_t)col0 * 4096 + tok0;

  auto stage_k = [&](const bf16_t* Kg, bf16_t* Ksn) {
    async16(Kg + (size_t)srow * 1024 + sxk, Ksn + kdst);
    async16(Kg + (size_t)(srow + 64) * 1024 + sxk, Ksn + kdst + 4096);
  };

  auto compute_tile = [&](const bf16_t* Ksc, const bf16_t* Vsc) {
#pragma unroll
    for (int c = 0; c < 8; ++c) {
      const bf16x8 kf0 = ldg8(&Ksc[c * 1024 + koff0]);
      const bf16x8 kf1 = ldg8(&Ksc[c * 1024 + koff1]);
      f32x4 sT = {0.f, 0.f, 0.f, 0.f};
      __builtin_amdgcn_s_setprio(1);
      sT = MFMA(kf0, qf[0], sT);
      sT = MFMA(kf1, qf[1], sT);
      __builtin_amdgcn_s_setprio(0);
      const float p0 = fast_exp2(sT.x);
      const float p1 = fast_exp2(sT.y);
      const float p2 = fast_exp2(sT.z);
      const float p3 = fast_exp2(sT.w);
      bf16x4 pb;
      pb[0] = (__bf16)p0; pb[1] = (__bf16)p1;
      pb[2] = (__bf16)p2; pb[3] = (__bf16)p3;
      lsum += (p0 + p1) + (p2 + p3);
      __builtin_amdgcn_s_setprio(1);
#pragma unroll
      for (int ht = 0; ht < 4; ++ht) {
        const bf16x4 vf = ldg4(&Vsc[ht * 16 * VPADA + voff + c * 16]);
        o[ht] = mfma16(vf, pb, o[ht]);
      }
      __builtin_amdgcn_s_setprio(0);
    }
  };

  // prologue: stage tile 0 into buffer 0
  {
    const bf16x8 v0 = ldg8(Vg0 + (size_t)srow * 4096 + sxv);
    const bf16x8 v1 = ldg8(Vg0 + (size_t)srow * 4096 + sxv + 64);
    stage_k(Kg0, Ks0);
    st8(&Vs0[srow * VPADA + sxv], v0);
    st8(&Vs0[srow * VPADA + sxv + 64], v1);
  }

#pragma unroll 1
  for (int t = 0; t < 16; t += 2) {
    // --- step A: compute buf0 (tile t), stage tile t+1 into buf1 ---
    __syncthreads();  // buf0 staged; drains prior-iteration asyncs (landed)
    {
      const bf16_t* Kg = Kg0 + (size_t)(t + 1) * 131072;
      const bf16_t* Vg = Vg0 + (t + 1) * 128;
      const bf16x8 v0 = ldg8(Vg + (size_t)srow * 4096 + sxv);
      const bf16x8 v1 = ldg8(Vg + (size_t)srow * 4096 + sxv + 64);
      stage_k(Kg, Ks1);
      compute_tile(Ks0, Vs0);
      st8(&Vs1[srow * VPADA + sxv], v0);
      st8(&Vs1[srow * VPADA + sxv + 64], v1);
    }
    // --- step B: compute buf1 (tile t+1), stage tile t+2 into buf0 ---
    __syncthreads();
    if (t + 2 < 16) {
      const bf16_t* Kg = Kg0 + (size_t)(t + 2) * 131072;
      const bf16_t* Vg = Vg0 + (t + 2) * 128;
      const bf16x8 v0 = ldg8(Vg + (size_t)srow * 4096 + sxv);
      const bf16x8 v1 = ldg8(Vg + (size_t)srow * 4096 + sxv + 64);
      stage_k(Kg, Ks0);
      compute_tile(Ks1, Vs1);
      st8(&Vs0[srow * VPADA + sxv], v0);
      st8(&Vs0[srow * VPADA + sxv + 64], v1);
    } else {
      compute_tile(Ks1, Vs1);
    }
  }

  // make sure all waves are done with Ks/Vs before overlaying scratch
  __syncthreads();

  float* Ow = &Osc[wave * 64 * 17];
  {
    // l: per-lane partial over kv ≡ lq quadrant; reduce across lq
    float ls = lsum;
    ls += __shfl_xor(ls, 16);
    ls += __shfl_xor(ls, 32);
    const float invl = 1.f / ls;

    // wave-private transpose bounce (in-wave DS ordering, no barrier)
#pragma unroll
    for (int ht = 0; ht < 4; ++ht)
#pragma unroll
      for (int r = 0; r < 4; ++r)
        Ow[(ht * 16 + lq * 4 + r) * 17 + lr] = o[ht][r] * invl;

    const int qq = lane >> 2;          // 0..15
    const int hc = (lane & 3) * 16;    // hd segment
    bf16x8 w0, w1;
#pragma unroll
    for (int i = 0; i < 8; ++i) {
      w0[i] = (__bf16)Ow[(hc + i) * 17 + qq];
      w1[i] = (__bf16)Ow[(hc + 8 + i) * 17 + qq];
    }
    bf16_t* dst = Ao + (tok0 + qblk + qq) * 1024 + col0 + hc;
    st8(dst, w0);
    st8(dst + 8, w1);
  }
}

extern "C" void kernel_launch(void* const* d_in, const int* in_sizes, int n_in,
                              void* d_out, int out_size, void* d_ws, size_t ws_size,
                              hipStream_t stream) {
  const float* x  = (const float*)d_in[0];
  const float* Wq = (const float*)d_in[1];
  const float* Wk = (const float*)d_in[2];
  const float* Wv = (const float*)d_in[3];
  const float* Wo = (const float*)d_in[4];
  const float* bo = (const float*)d_in[5];
  float* out = (float*)d_out;

  const size_t NTOK = 4096, DMODEL = 1024, WSZ = DMODEL * DMODEL;
  bf16_t* xb  = (bf16_t*)d_ws;
  bf16_t* Wqb = xb + NTOK * DMODEL;
  bf16_t* Wkb = Wqb + WSZ;
  bf16_t* Wvb = Wkb + WSZ;
  bf16_t* Wob = Wvb + WSZ;
  bf16_t* Q   = Wob + WSZ;
  bf16_t* Kp  = Q  + NTOK * DMODEL;
  bf16_t* Vt  = Kp + NTOK * DMODEL;            // [1024][4096] = V^T
  bf16_t* Ao  = Vt + NTOK * DMODEL;

  cvt_kernel<<<dim3(4096), 256, 0, stream>>>(x, Wq, Wk, Wv, Wo, xb, Wqb, Wkb, Wvb, Wob);
  qkv_kernel<<<dim3(256, 3), 256, 0, stream>>>(xb, Wqb, Wkb, Wvb, Q, Kp, Vt);
  attn_kernel<<<dim3(32, 16), 512, 0, stream>>>(Q, Kp, Vt, Ao);
  out_proj_kernel<<<dim3(512, 1), 256, 0, stream>>>(Ao, Wob, bo, out);
}

// Round 13
// 180.388 us; speedup vs baseline: 1.0077x; 1.0077x over previous
//
#include <hip/hip_runtime.h>
#include <hip/hip_bf16.h>

typedef __hip_bfloat16 bf16_t;
typedef __bf16 bf16x8 __attribute__((ext_vector_type(8)));      // 16x16x32 A/B frag
typedef __bf16 bf16x4 __attribute__((ext_vector_type(4)));      // 16x16x16 A/B frag
typedef short  s16x4  __attribute__((ext_vector_type(4)));
typedef float  f32x4  __attribute__((ext_vector_type(4)));      // C/D frag

#define MFMA(a, b, c) __builtin_amdgcn_mfma_f32_16x16x32_bf16((a), (b), (c), 0, 0, 0)

__device__ __forceinline__ f32x4 mfma16(bf16x4 a, bf16x4 b, f32x4 c) {
#if __has_builtin(__builtin_amdgcn_mfma_f32_16x16x16_bf16)
  return __builtin_amdgcn_mfma_f32_16x16x16_bf16(a, b, c, 0, 0, 0);
#else
  return __builtin_amdgcn_mfma_f32_16x16x16bf16_1k(
      __builtin_bit_cast(s16x4, a), __builtin_bit_cast(s16x4, b), c, 0, 0, 0);
#endif
}

// Raw v_exp_f32: skips ocml's denorm-range fixup (~4 extra VALU/exp).
__device__ __forceinline__ float fast_exp2(float x) {
#if __has_builtin(__builtin_amdgcn_exp2f)
  return __builtin_amdgcn_exp2f(x);
#else
  float r;
  asm("v_exp_f32 %0, %1" : "=v"(r) : "v"(x));
  return r;
#endif
}

__device__ __forceinline__ bf16x8 ldg8(const bf16_t* p) {
  return *reinterpret_cast<const bf16x8*>(p);
}
__device__ __forceinline__ bf16x4 ldg4(const bf16_t* p) {
  return *reinterpret_cast<const bf16x4*>(p);
}
__device__ __forceinline__ void st8(bf16_t* p, bf16x8 v) {
  *reinterpret_cast<bf16x8*>(p) = v;
}
__device__ __forceinline__ void store_out(bf16_t* p, float v) { *p = __float2bfloat16(v); }
__device__ __forceinline__ void store_out(float* p, float v)  { *p = v; }

// async global->LDS, 16B per lane. LDS dest is wave-uniform base + lane*16.
__device__ __forceinline__ void async16(const bf16_t* g, bf16_t* l) {
  __builtin_amdgcn_global_load_lds(
      (const __attribute__((address_space(1))) void*)g,
      (__attribute__((address_space(3))) void*)l, 16, 0, 0);
}

// ---------------------------------------------------------------------------
// f32 -> bf16 conversion; folds softmax scale (1/8 * log2e) into Wq.
// ---------------------------------------------------------------------------
__global__ __launch_bounds__(256) void cvt_kernel(
    const float* __restrict__ x,  const float* __restrict__ Wq,
    const float* __restrict__ Wk, const float* __restrict__ Wv,
    const float* __restrict__ Wo,
    bf16_t* __restrict__ xb,  bf16_t* __restrict__ Wqb,
    bf16_t* __restrict__ Wkb, bf16_t* __restrict__ Wvb,
    bf16_t* __restrict__ Wob) {
  const int bid = blockIdx.x;
  const float* src; bf16_t* dst; size_t base;
  float scl = 1.0f;
  if (bid < 2048)      { src = x;  dst = xb;  base = (size_t)bid * 2048; }
  else if (bid < 2560) { src = Wq; dst = Wqb; base = (size_t)(bid - 2048) * 2048;
                         scl = 0.180336878f; }  // 0.125 * log2(e)
  else if (bid < 3072) { src = Wk; dst = Wkb; base = (size_t)(bid - 2560) * 2048; }
  else if (bid < 3584) { src = Wv; dst = Wvb; base = (size_t)(bid - 3072) * 2048; }
  else                 { src = Wo; dst = Wob; base = (size_t)(bid - 3584) * 2048; }
  const size_t i0 = base + (size_t)threadIdx.x * 8;
  const float4 f0 = *reinterpret_cast<const float4*>(src + i0);
  const float4 f1 = *reinterpret_cast<const float4*>(src + i0 + 4);
  bf16x8 v;
  v[0] = (__bf16)(f0.x * scl); v[1] = (__bf16)(f0.y * scl);
  v[2] = (__bf16)(f0.z * scl); v[3] = (__bf16)(f0.w * scl);
  v[4] = (__bf16)(f1.x * scl); v[5] = (__bf16)(f1.y * scl);
  v[6] = (__bf16)(f1.z * scl); v[7] = (__bf16)(f1.w * scl);
  st8(dst + i0, v);
}

// ---------------------------------------------------------------------------
// GEMM tile 128x64 (round-13: now used by BOTH qkv and out_proj).
// m97-style staging: stage -> barrier -> compute, BK=64, XOR-chunk swizzle.
// [History: R8 dbuf BK=32 hurt (+4.7us, barrier drains the prefetch);
// R11 counted-vmcnt 3-buffer hurt (+4.7us, T4 needs 8-phase regime).
// R10: out_proj 128x128->128x64 (1->2 blocks/CU) was -7us: unsynced
// co-resident BLOCKS hide each other's drain windows (unlike waves in a
// block, which all arrive at the same barrier - R9's +5% lesson).]
// ---------------------------------------------------------------------------
#define GK 1024

template <typename OutT, bool BIAS>
__device__ __forceinline__ void gemm_tile_n64(
    const bf16_t* __restrict__ A, const bf16_t* __restrict__ B,
    OutT* __restrict__ C, const float* __restrict__ bias,
    int bm, int bn, int ldc, bf16_t* As, bf16_t* Bs) {
  const int tid  = threadIdx.x;
  const int lane = tid & 63;
  const int wave = tid >> 6;
  const int wm   = (wave & 1) << 6;    // 0/64
  const int wn   = (wave >> 1) << 5;   // 0/32
  const int lr   = lane & 15;
  const int lq   = lane >> 4;

  const int srow = tid >> 3;                        // 0..31
  const int sx   = ((tid & 7) ^ (srow & 7)) << 3;   // swizzled source offset

  const bf16_t* Ag = A + (size_t)(bm + srow) * GK + sx;
  const bf16_t* Bg = B + (size_t)(bn + srow) * GK + sx;
  bf16_t* Asw = As + wave * 512;
  bf16_t* Bsw = Bs + wave * 512;

  f32x4 acc[4][2];
#pragma unroll
  for (int i = 0; i < 4; ++i)
#pragma unroll
    for (int j = 0; j < 2; ++j) acc[i][j] = (f32x4){0.f, 0.f, 0.f, 0.f};

  for (int k0 = 0; k0 < GK; k0 += 64) {
    __syncthreads();
#pragma unroll
    for (int g = 0; g < 4; ++g)
      async16(Ag + k0 + (size_t)(g * 32) * GK, Asw + g * 2048);
#pragma unroll
    for (int g = 0; g < 2; ++g)
      async16(Bg + k0 + (size_t)(g * 32) * GK, Bsw + g * 2048);
    __syncthreads();
#pragma unroll
    for (int ks = 0; ks < 2; ++ks) {
      bf16x8 af[4], bf[2];
      const int chs = ((ks * 4 + lq) ^ (lr & 7)) << 3;
#pragma unroll
      for (int i = 0; i < 4; ++i)
        af[i] = ldg8(&As[(wm + i * 16 + lr) * 64 + chs]);
#pragma unroll
      for (int i = 0; i < 2; ++i)
        bf[i] = ldg8(&Bs[(wn + i * 16 + lr) * 64 + chs]);
#pragma unroll
      for (int mi = 0; mi < 4; ++mi)
#pragma unroll
        for (int ni = 0; ni < 2; ++ni)
          acc[mi][ni] = MFMA(af[mi], bf[ni], acc[mi][ni]);
    }
  }

  // C/D layout: col = lane&15, row = (lane>>4)*4 + r  (m89-verified)
#pragma unroll
  for (int ni = 0; ni < 2; ++ni) {
    const int col = bn + wn + ni * 16 + lr;
    float bv = 0.f;
    if (BIAS) bv = bias[col];
#pragma unroll
    for (int mi = 0; mi < 4; ++mi) {
#pragma unroll
      for (int r = 0; r < 4; ++r) {
        const int row = bm + wm + mi * 16 + lq * 4 + r;
        store_out(&C[(size_t)row * ldc + col], acc[mi][ni][r] + bv);
      }
    }
  }
}

// ---------------------------------------------------------------------------
// qkv, round 13: 128x64 tiles -> grid 512x3 = 1536 blocks = 6 blocks/CU
// (was 768 = 3/CU, grid-limited). Co-resident unsynced blocks hide each
// other's stage->barrier drain windows (out_proj's measured -7us lever).
// XCD property kept: z<2 blocks sharing an x-panel have fixed bid&7;
// z=2 blocks sharing a Wv A-panel have fixed bid&7.
// z=0: Q = x Wq^T; z=1: K = x Wk^T; z=2: Vt = Wv x^T [1024x4096]
// ---------------------------------------------------------------------------
__global__ __launch_bounds__(256) void qkv_kernel(
    const bf16_t* __restrict__ x, const bf16_t* __restrict__ Wq,
    const bf16_t* __restrict__ Wk, const bf16_t* __restrict__ Wv,
    bf16_t* __restrict__ Q, bf16_t* __restrict__ Kp, bf16_t* __restrict__ Vt) {
  __shared__ alignas(16) bf16_t As[128 * 64];
  __shared__ alignas(16) bf16_t Bs[64 * 64];
  const int bid = blockIdx.x;                      // 0..511
  const int z   = blockIdx.y;
  if (z == 0) {
    gemm_tile_n64<bf16_t, false>(x, Wq, Q, nullptr,
                                 (bid & 31) * 128, (bid >> 5) * 64, 1024, As, Bs);
  } else if (z == 1) {
    gemm_tile_n64<bf16_t, false>(x, Wk, Kp, nullptr,
                                 (bid & 31) * 128, (bid >> 5) * 64, 1024, As, Bs);
  } else {
    // M = Wv rows (8 tiles of 128), N = tokens (64 tiles of 64)
    gemm_tile_n64<bf16_t, false>(Wv, x, Vt, nullptr,
                                 (bid & 7) * 128, (bid >> 3) * 64, 4096, As, Bs);
  }
}

__global__ __launch_bounds__(256) void out_proj_kernel(
    const bf16_t* __restrict__ Ao, const bf16_t* __restrict__ Wo,
    const float* __restrict__ bias, float* __restrict__ out) {
  __shared__ alignas(16) bf16_t As[128 * 64];
  __shared__ alignas(16) bf16_t Bs[64 * 64];
  const int bid = blockIdx.x;
  gemm_tile_n64<float, true>(Ao, Wo, out, bias, (bid & 31) * 128,
                             (bid >> 5) * 64, 1024, As, Bs);
}

// ---------------------------------------------------------------------------
// Attention (round-10 verified, 52.5us; re-measured 51.7 r11): 8 waves x
// 16 q-rows, KVBLK=128, dbuf K/V, register P, raw-exp softmax.
// [R12 T5 setprio: HURT (52.5->56.7) — the setprio pairs split compiler
// scheduling regions, broke V ds_read batching, bank conflicts 262K->4.5M
// (17x). Reverted byte-exact. R9 occ 2x: +5%; R10 KVBLK 2x: +2.6%;
// MfmaUtil 39 + VALU 42 = 81% combined -> near issue-bound plateau.]
// ---------------------------------------------------------------------------
#define VPADA 132

__global__ __launch_bounds__(512, 4) void attn_kernel(
    const bf16_t* __restrict__ Q, const bf16_t* __restrict__ Kp,
    const bf16_t* __restrict__ Vt, bf16_t* __restrict__ Ao) {
  // Ks0|Ks1: [128 kv][64 hd] swizzled (16384 B each)
  // Vs0|Vs1: [64 hd][VPADA kv] (16896 B each).  Osc overlay: 34816 B.
  __shared__ alignas(16) char smem_raw[2 * 16384 + 2 * 16896];  // 66560 B
  bf16_t* Ks0 = (bf16_t*)smem_raw;
  bf16_t* Ks1 = Ks0 + 8192;
  bf16_t* Vs0 = (bf16_t*)(smem_raw + 32768);
  bf16_t* Vs1 = Vs0 + 64 * VPADA;
  float*  Osc = (float*)smem_raw;                  // epilogue scratch

  const int tid  = threadIdx.x;                    // 0..511
  const int lane = tid & 63;
  const int wave = tid >> 6;                       // 0..7
  const int lr   = lane & 15;
  const int lq   = lane >> 4;
  const int bh   = blockIdx.x;
  const int qt   = blockIdx.y;
  const int b    = bh >> 4;
  const int h    = bh & 15;
  const size_t tok0 = (size_t)b * 2048;
  const int col0 = h * 64;
  const int qblk = qt * 128 + wave * 16;           // wave's 16 q-rows

  // Q B-frags (n = q = lane&15, k = hd = c*32 + lq*8 + i), held in regs
  bf16x8 qf[2];
  {
    const size_t qrow = tok0 + qblk + lr;
#pragma unroll
    for (int c = 0; c < 2; ++c)
      qf[c] = ldg8(&Q[qrow * 1024 + col0 + c * 32 + lq * 8]);
  }

  f32x4 o[4];  // O^T accum: D[m=hd=ht*16+lq*4+r][n=q=lr]
#pragma unroll
  for (int i = 0; i < 4; ++i) o[i] = (f32x4){0.f, 0.f, 0.f, 0.f};
  float lsum = 0.f;

  // staging: K rows srow, srow+64 (same parity -> same swizzle); V rows
  // srow (hd), kv chunks sxv and sxv+64.
  const int srow = tid >> 3;                       // 0..63
  const int sxk  = ((tid & 7) ^ (srow & 7)) << 3;  // K swizzled source chunk
  const int sxv  = (tid & 7) << 3;
  const int kdst = wave * 512;                     // wave-uniform LDS elems

  // frag-read LDS offsets (elems)
  const int koff0 = lr * 64 + ((lq ^ (lr & 7)) << 3);
  const int koff1 = lr * 64 + (((lq + 4) ^ (lr & 7)) << 3);
  const int voff  = lr * VPADA + lq * 4;

  const bf16_t* Kg0 = Kp + tok0 * 1024 + col0;
  const bf16_t* Vg0 = Vt + (size_t)col0 * 4096 + tok0;

  auto stage_k = [&](const bf16_t* Kg, bf16_t* Ksn) {
    async16(Kg + (size_t)srow * 1024 + sxk, Ksn + kdst);
    async16(Kg + (size_t)(srow + 64) * 1024 + sxk, Ksn + kdst + 4096);
  };

  auto compute_tile = [&](const bf16_t* Ksc, const bf16_t* Vsc) {
#pragma unroll
    for (int c = 0; c < 8; ++c) {
      const bf16x8 kf0 = ldg8(&Ksc[c * 1024 + koff0]);
      const bf16x8 kf1 = ldg8(&Ksc[c * 1024 + koff1]);
      f32x4 sT = {0.f, 0.f, 0.f, 0.f};
      sT = MFMA(kf0, qf[0], sT);
      sT = MFMA(kf1, qf[1], sT);
      const float p0 = fast_exp2(sT.x);
      const float p1 = fast_exp2(sT.y);
      const float p2 = fast_exp2(sT.z);
      const float p3 = fast_exp2(sT.w);
      bf16x4 pb;
      pb[0] = (__bf16)p0; pb[1] = (__bf16)p1;
      pb[2] = (__bf16)p2; pb[3] = (__bf16)p3;
      lsum += (p0 + p1) + (p2 + p3);
#pragma unroll
      for (int ht = 0; ht < 4; ++ht) {
        const bf16x4 vf = ldg4(&Vsc[ht * 16 * VPADA + voff + c * 16]);
        o[ht] = mfma16(vf, pb, o[ht]);
      }
    }
  };

  // prologue: stage tile 0 into buffer 0
  {
    const bf16x8 v0 = ldg8(Vg0 + (size_t)srow * 4096 + sxv);
    const bf16x8 v1 = ldg8(Vg0 + (size_t)srow * 4096 + sxv + 64);
    stage_k(Kg0, Ks0);
    st8(&Vs0[srow * VPADA + sxv], v0);
    st8(&Vs0[srow * VPADA + sxv + 64], v1);
  }

#pragma unroll 1
  for (int t = 0; t < 16; t += 2) {
    // --- step A: compute buf0 (tile t), stage tile t+1 into buf1 ---
    __syncthreads();  // buf0 staged; drains prior-iteration asyncs (landed)
    {
      const bf16_t* Kg = Kg0 + (size_t)(t + 1) * 131072;
      const bf16_t* Vg = Vg0 + (t + 1) * 128;
      const bf16x8 v0 = ldg8(Vg + (size_t)srow * 4096 + sxv);
      const bf16x8 v1 = ldg8(Vg + (size_t)srow * 4096 + sxv + 64);
      stage_k(Kg, Ks1);
      compute_tile(Ks0, Vs0);
      st8(&Vs1[srow * VPADA + sxv], v0);
      st8(&Vs1[srow * VPADA + sxv + 64], v1);
    }
    // --- step B: compute buf1 (tile t+1), stage tile t+2 into buf0 ---
    __syncthreads();
    if (t + 2 < 16) {
      const bf16_t* Kg = Kg0 + (size_t)(t + 2) * 131072;
      const bf16_t* Vg = Vg0 + (t + 2) * 128;
      const bf16x8 v0 = ldg8(Vg + (size_t)srow * 4096 + sxv);
      const bf16x8 v1 = ldg8(Vg + (size_t)srow * 4096 + sxv + 64);
      stage_k(Kg, Ks0);
      compute_tile(Ks1, Vs1);
      st8(&Vs0[srow * VPADA + sxv], v0);
      st8(&Vs0[srow * VPADA + sxv + 64], v1);
    } else {
      compute_tile(Ks1, Vs1);
    }
  }

  // make sure all waves are done with Ks/Vs before overlaying scratch
  __syncthreads();

  float* Ow = &Osc[wave * 64 * 17];
  {
    // l: per-lane partial over kv ≡ lq quadrant; reduce across lq
    float ls = lsum;
    ls += __shfl_xor(ls, 16);
    ls += __shfl_xor(ls, 32);
    const float invl = 1.f / ls;

    // wave-private transpose bounce (in-wave DS ordering, no barrier)
#pragma unroll
    for (int ht = 0; ht < 4; ++ht)
#pragma unroll
      for (int r = 0; r < 4; ++r)
        Ow[(ht * 16 + lq * 4 + r) * 17 + lr] = o[ht][r] * invl;

    const int qq = lane >> 2;          // 0..15
    const int hc = (lane & 3) * 16;    // hd segment
    bf16x8 w0, w1;
#pragma unroll
    for (int i = 0; i < 8; ++i) {
      w0[i] = (__bf16)Ow[(hc + i) * 17 + qq];
      w1[i] = (__bf16)Ow[(hc + 8 + i) * 17 + qq];
    }
    bf16_t* dst = Ao + (tok0 + qblk + qq) * 1024 + col0 + hc;
    st8(dst, w0);
    st8(dst + 8, w1);
  }
}

extern "C" void kernel_launch(void* const* d_in, const int* in_sizes, int n_in,
                              void* d_out, int out_size, void* d_ws, size_t ws_size,
                              hipStream_t stream) {
  const float* x  = (const float*)d_in[0];
  const float* Wq = (const float*)d_in[1];
  const float* Wk = (const float*)d_in[2];
  const float* Wv = (const float*)d_in[3];
  const float* Wo = (const float*)d_in[4];
  const float* bo = (const float*)d_in[5];
  float* out = (float*)d_out;

  const size_t NTOK = 4096, DMODEL = 1024, WSZ = DMODEL * DMODEL;
  bf16_t* xb  = (bf16_t*)d_ws;
  bf16_t* Wqb = xb + NTOK * DMODEL;
  bf16_t* Wkb = Wqb + WSZ;
  bf16_t* Wvb = Wkb + WSZ;
  bf16_t* Wob = Wvb + WSZ;
  bf16_t* Q   = Wob + WSZ;
  bf16_t* Kp  = Q  + NTOK * DMODEL;
  bf16_t* Vt  = Kp + NTOK * DMODEL;            // [1024][4096] = V^T
  bf16_t* Ao  = Vt + NTOK * DMODEL;

  cvt_kernel<<<dim3(4096), 256, 0, stream>>>(x, Wq, Wk, Wv, Wo, xb, Wqb, Wkb, Wvb, Wob);
  qkv_kernel<<<dim3(512, 3), 256, 0, stream>>>(xb, Wqb, Wkb, Wvb, Q, Kp, Vt);
  attn_kernel<<<dim3(32, 16), 512, 0, stream>>>(Q, Kp, Vt, Ao);
  out_proj_kernel<<<dim3(512, 1), 256, 0, stream>>>(Ao, Wob, bo, out);
}

// Round 14
// 175.029 us; speedup vs baseline: 1.0386x; 1.0306x over previous
//
#include <hip/hip_runtime.h>
#include <hip/hip_bf16.h>

typedef __hip_bfloat16 bf16_t;
typedef __bf16 bf16x8 __attribute__((ext_vector_type(8)));      // 16x16x32 A/B frag
typedef __bf16 bf16x4 __attribute__((ext_vector_type(4)));      // 16x16x16 A/B frag
typedef short  s16x4  __attribute__((ext_vector_type(4)));
typedef float  f32x4  __attribute__((ext_vector_type(4)));      // C/D frag

#define MFMA(a, b, c) __builtin_amdgcn_mfma_f32_16x16x32_bf16((a), (b), (c), 0, 0, 0)

__device__ __forceinline__ f32x4 mfma16(bf16x4 a, bf16x4 b, f32x4 c) {
#if __has_builtin(__builtin_amdgcn_mfma_f32_16x16x16_bf16)
  return __builtin_amdgcn_mfma_f32_16x16x16_bf16(a, b, c, 0, 0, 0);
#else
  return __builtin_amdgcn_mfma_f32_16x16x16bf16_1k(
      __builtin_bit_cast(s16x4, a), __builtin_bit_cast(s16x4, b), c, 0, 0, 0);
#endif
}

// Raw v_exp_f32: skips ocml's denorm-range fixup (~4 extra VALU/exp).
__device__ __forceinline__ float fast_exp2(float x) {
#if __has_builtin(__builtin_amdgcn_exp2f)
  return __builtin_amdgcn_exp2f(x);
#else
  float r;
  asm("v_exp_f32 %0, %1" : "=v"(r) : "v"(x));
  return r;
#endif
}

__device__ __forceinline__ bf16x8 ldg8(const bf16_t* p) {
  return *reinterpret_cast<const bf16x8*>(p);
}
__device__ __forceinline__ bf16x4 ldg4(const bf16_t* p) {
  return *reinterpret_cast<const bf16x4*>(p);
}
__device__ __forceinline__ void st8(bf16_t* p, bf16x8 v) {
  *reinterpret_cast<bf16x8*>(p) = v;
}
__device__ __forceinline__ void store_out(bf16_t* p, float v) { *p = __float2bfloat16(v); }
__device__ __forceinline__ void store_out(float* p, float v)  { *p = v; }

// async global->LDS, 16B per lane. LDS dest is wave-uniform base + lane*16.
__device__ __forceinline__ void async16(const bf16_t* g, bf16_t* l) {
  __builtin_amdgcn_global_load_lds(
      (const __attribute__((address_space(1))) void*)g,
      (__attribute__((address_space(3))) void*)l, 16, 0, 0);
}

// ---------------------------------------------------------------------------
// f32 -> bf16 conversion; folds softmax scale (1/8 * log2e) into Wq.
// ---------------------------------------------------------------------------
__global__ __launch_bounds__(256) void cvt_kernel(
    const float* __restrict__ x,  const float* __restrict__ Wq,
    const float* __restrict__ Wk, const float* __restrict__ Wv,
    const float* __restrict__ Wo,
    bf16_t* __restrict__ xb,  bf16_t* __restrict__ Wqb,
    bf16_t* __restrict__ Wkb, bf16_t* __restrict__ Wvb,
    bf16_t* __restrict__ Wob) {
  const int bid = blockIdx.x;
  const float* src; bf16_t* dst; size_t base;
  float scl = 1.0f;
  if (bid < 2048)      { src = x;  dst = xb;  base = (size_t)bid * 2048; }
  else if (bid < 2560) { src = Wq; dst = Wqb; base = (size_t)(bid - 2048) * 2048;
                         scl = 0.180336878f; }  // 0.125 * log2(e)
  else if (bid < 3072) { src = Wk; dst = Wkb; base = (size_t)(bid - 2560) * 2048; }
  else if (bid < 3584) { src = Wv; dst = Wvb; base = (size_t)(bid - 3072) * 2048; }
  else                 { src = Wo; dst = Wob; base = (size_t)(bid - 3584) * 2048; }
  const size_t i0 = base + (size_t)threadIdx.x * 8;
  const float4 f0 = *reinterpret_cast<const float4*>(src + i0);
  const float4 f1 = *reinterpret_cast<const float4*>(src + i0 + 4);
  bf16x8 v;
  v[0] = (__bf16)(f0.x * scl); v[1] = (__bf16)(f0.y * scl);
  v[2] = (__bf16)(f0.z * scl); v[3] = (__bf16)(f0.w * scl);
  v[4] = (__bf16)(f1.x * scl); v[5] = (__bf16)(f1.y * scl);
  v[6] = (__bf16)(f1.z * scl); v[7] = (__bf16)(f1.w * scl);
  st8(dst + i0, v);
}

// ---------------------------------------------------------------------------
// GEMM tile (round-2/10 verified structure): C[128x128]=A[128xK]*B[128xK]^T,
// K=1024, BK=64, global_load_lds width-16 staging with XOR-chunk swizzle.
// [R8 dbuf BK=32: hurt (+4.7us, barrier drains prefetch). R11 counted-vmcnt
// 3-buffer: hurt (+4.7us, T4 needs 8-phase regime). R13 qkv 128x64 split:
// hurt (+4.3us, staging volume per output 1.5x). At 64-VGPR accumulators,
// 128x128 is the staging-ratio optimum; this m97-style structure is the
// measured best of four schedule variants for K=1024.]
// ---------------------------------------------------------------------------
#define GK 1024

template <typename OutT, bool BIAS>
__device__ __forceinline__ void gemm_tile(
    const bf16_t* __restrict__ A, const bf16_t* __restrict__ B,
    OutT* __restrict__ C, const float* __restrict__ bias,
    int bm, int bn, int ldc, bf16_t* As, bf16_t* Bs) {
  const int tid  = threadIdx.x;
  const int lane = tid & 63;
  const int wave = tid >> 6;
  const int wm   = (wave & 1) << 6;
  const int wn   = (wave >> 1) << 6;
  const int lr   = lane & 15;
  const int lq   = lane >> 4;

  const int srow = tid >> 3;                        // 0..31
  const int sx   = ((tid & 7) ^ (srow & 7)) << 3;   // swizzled source offset

  const bf16_t* Ag = A + (size_t)(bm + srow) * GK + sx;
  const bf16_t* Bg = B + (size_t)(bn + srow) * GK + sx;
  bf16_t* Asw = As + wave * 512;
  bf16_t* Bsw = Bs + wave * 512;

  f32x4 acc[4][4];
#pragma unroll
  for (int i = 0; i < 4; ++i)
#pragma unroll
    for (int j = 0; j < 4; ++j) acc[i][j] = (f32x4){0.f, 0.f, 0.f, 0.f};

  for (int k0 = 0; k0 < GK; k0 += 64) {
    __syncthreads();
#pragma unroll
    for (int g = 0; g < 4; ++g) {
      async16(Ag + k0 + (size_t)(g * 32) * GK, Asw + g * 2048);
      async16(Bg + k0 + (size_t)(g * 32) * GK, Bsw + g * 2048);
    }
    __syncthreads();
#pragma unroll
    for (int ks = 0; ks < 2; ++ks) {
      bf16x8 af[4], bf[4];
      const int chs = ((ks * 4 + lq) ^ (lr & 7)) << 3;
#pragma unroll
      for (int i = 0; i < 4; ++i) {
        af[i] = ldg8(&As[(wm + i * 16 + lr) * 64 + chs]);
        bf[i] = ldg8(&Bs[(wn + i * 16 + lr) * 64 + chs]);
      }
#pragma unroll
      for (int mi = 0; mi < 4; ++mi)
#pragma unroll
        for (int ni = 0; ni < 4; ++ni)
          acc[mi][ni] = MFMA(af[mi], bf[ni], acc[mi][ni]);
    }
  }

  // C/D layout: col = lane&15, row = (lane>>4)*4 + r  (m89-verified)
#pragma unroll
  for (int ni = 0; ni < 4; ++ni) {
    const int col = bn + wn + ni * 16 + lr;
    float bv = 0.f;
    if (BIAS) bv = bias[col];
#pragma unroll
    for (int mi = 0; mi < 4; ++mi) {
#pragma unroll
      for (int r = 0; r < 4; ++r) {
        const int row = bm + wm + mi * 16 + lq * 4 + r;
        store_out(&C[(size_t)row * ldc + col], acc[mi][ni][r] + bv);
      }
    }
  }
}

// ---------------------------------------------------------------------------
// GEMM tile 128x64 (out_proj, round-10 verified): out_proj at 256 blocks was
// 1 block/CU; N-split to 64 cols doubles the grid to 512 (2/CU). -7us.
// [R13: the same split applied to qkv (3->6 blocks/CU) HURT — the A-panel
// re-staging tax only pays off when escaping 1 block/CU.]
// ---------------------------------------------------------------------------
template <typename OutT, bool BIAS>
__device__ __forceinline__ void gemm_tile_n64(
    const bf16_t* __restrict__ A, const bf16_t* __restrict__ B,
    OutT* __restrict__ C, const float* __restrict__ bias,
    int bm, int bn, int ldc, bf16_t* As, bf16_t* Bs) {
  const int tid  = threadIdx.x;
  const int lane = tid & 63;
  const int wave = tid >> 6;
  const int wm   = (wave & 1) << 6;    // 0/64
  const int wn   = (wave >> 1) << 5;   // 0/32
  const int lr   = lane & 15;
  const int lq   = lane >> 4;

  const int srow = tid >> 3;                        // 0..31
  const int sx   = ((tid & 7) ^ (srow & 7)) << 3;   // swizzled source offset

  const bf16_t* Ag = A + (size_t)(bm + srow) * GK + sx;
  const bf16_t* Bg = B + (size_t)(bn + srow) * GK + sx;
  bf16_t* Asw = As + wave * 512;
  bf16_t* Bsw = Bs + wave * 512;

  f32x4 acc[4][2];
#pragma unroll
  for (int i = 0; i < 4; ++i)
#pragma unroll
    for (int j = 0; j < 2; ++j) acc[i][j] = (f32x4){0.f, 0.f, 0.f, 0.f};

  for (int k0 = 0; k0 < GK; k0 += 64) {
    __syncthreads();
#pragma unroll
    for (int g = 0; g < 4; ++g)
      async16(Ag + k0 + (size_t)(g * 32) * GK, Asw + g * 2048);
#pragma unroll
    for (int g = 0; g < 2; ++g)
      async16(Bg + k0 + (size_t)(g * 32) * GK, Bsw + g * 2048);
    __syncthreads();
#pragma unroll
    for (int ks = 0; ks < 2; ++ks) {
      bf16x8 af[4], bf[2];
      const int chs = ((ks * 4 + lq) ^ (lr & 7)) << 3;
#pragma unroll
      for (int i = 0; i < 4; ++i)
        af[i] = ldg8(&As[(wm + i * 16 + lr) * 64 + chs]);
#pragma unroll
      for (int i = 0; i < 2; ++i)
        bf[i] = ldg8(&Bs[(wn + i * 16 + lr) * 64 + chs]);
#pragma unroll
      for (int mi = 0; mi < 4; ++mi)
#pragma unroll
        for (int ni = 0; ni < 2; ++ni)
          acc[mi][ni] = MFMA(af[mi], bf[ni], acc[mi][ni]);
    }
  }

#pragma unroll
  for (int ni = 0; ni < 2; ++ni) {
    const int col = bn + wn + ni * 16 + lr;
    float bv = 0.f;
    if (BIAS) bv = bias[col];
#pragma unroll
    for (int mi = 0; mi < 4; ++mi) {
#pragma unroll
      for (int r = 0; r < 4; ++r) {
        const int row = bm + wm + mi * 16 + lq * 4 + r;
        store_out(&C[(size_t)row * ldc + col], acc[mi][ni][r] + bv);
      }
    }
  }
}

// XCD-aware remap: same-x-tile blocks share bid%8 -> same XCD L2.
// z=0: Q = x Wq^T;  z=1: K = x Wk^T;  z=2: Vt = Wv x^T [1024x4096]
__global__ __launch_bounds__(256) void qkv_kernel(
    const bf16_t* __restrict__ x, const bf16_t* __restrict__ Wq,
    const bf16_t* __restrict__ Wk, const bf16_t* __restrict__ Wv,
    bf16_t* __restrict__ Q, bf16_t* __restrict__ Kp, bf16_t* __restrict__ Vt) {
  __shared__ alignas(16) bf16_t As[128 * 64];
  __shared__ alignas(16) bf16_t Bs[128 * 64];
  const int bid = blockIdx.x;
  const int z   = blockIdx.y;
  const int mt  = (bid & 31) * 128;   // x token-tile; XCD = bid%8 = mt-tile%8
  const int nt  = (bid >> 5) * 128;
  if (z == 0) {
    gemm_tile<bf16_t, false>(x, Wq, Q, nullptr, mt, nt, 1024, As, Bs);
  } else if (z == 1) {
    gemm_tile<bf16_t, false>(x, Wk, Kp, nullptr, mt, nt, 1024, As, Bs);
  } else {
    gemm_tile<bf16_t, false>(Wv, x, Vt, nullptr, nt, mt, 4096, As, Bs);
  }
}

__global__ __launch_bounds__(256) void out_proj_kernel(
    const bf16_t* __restrict__ Ao, const bf16_t* __restrict__ Wo,
    const float* __restrict__ bias, float* __restrict__ out) {
  __shared__ alignas(16) bf16_t As[128 * 64];
  __shared__ alignas(16) bf16_t Bs[64 * 64];
  const int bid = blockIdx.x;
  gemm_tile_n64<float, true>(Ao, Wo, out, bias, (bid & 31) * 128,
                             (bid >> 5) * 64, 1024, As, Bs);
}

// ---------------------------------------------------------------------------
// Attention (round-10 verified, 52.5us): 8 waves x 16 q-rows, KVBLK=128,
// dbuf K/V, register P, raw-exp softmax.
// [R12 T5 setprio: HURT (52.5->56.7, bank conflicts 262K->4.5M — codegen
// perturbation broke V ds_read batching). R9 occ 2x: +5%; R10 KVBLK 2x:
// +2.6%; R3 x32-PV: -48%. MfmaUtil 39 + VALU 42 = 81% combined issue ->
// structural plateau for this dataflow.]
// ---------------------------------------------------------------------------
#define VPADA 132

__global__ __launch_bounds__(512, 4) void attn_kernel(
    const bf16_t* __restrict__ Q, const bf16_t* __restrict__ Kp,
    const bf16_t* __restrict__ Vt, bf16_t* __restrict__ Ao) {
  // Ks0|Ks1: [128 kv][64 hd] swizzled (16384 B each)
  // Vs0|Vs1: [64 hd][VPADA kv] (16896 B each).  Osc overlay: 34816 B.
  __shared__ alignas(16) char smem_raw[2 * 16384 + 2 * 16896];  // 66560 B
  bf16_t* Ks0 = (bf16_t*)smem_raw;
  bf16_t* Ks1 = Ks0 + 8192;
  bf16_t* Vs0 = (bf16_t*)(smem_raw + 32768);
  bf16_t* Vs1 = Vs0 + 64 * VPADA;
  float*  Osc = (float*)smem_raw;                  // epilogue scratch

  const int tid  = threadIdx.x;                    // 0..511
  const int lane = tid & 63;
  const int wave = tid >> 6;                       // 0..7
  const int lr   = lane & 15;
  const int lq   = lane >> 4;
  const int bh   = blockIdx.x;
  const int qt   = blockIdx.y;
  const int b    = bh >> 4;
  const int h    = bh & 15;
  const size_t tok0 = (size_t)b * 2048;
  const int col0 = h * 64;
  const int qblk = qt * 128 + wave * 16;           // wave's 16 q-rows

  // Q B-frags (n = q = lane&15, k = hd = c*32 + lq*8 + i), held in regs
  bf16x8 qf[2];
  {
    const size_t qrow = tok0 + qblk + lr;
#pragma unroll
    for (int c = 0; c < 2; ++c)
      qf[c] = ldg8(&Q[qrow * 1024 + col0 + c * 32 + lq * 8]);
  }

  f32x4 o[4];  // O^T accum: D[m=hd=ht*16+lq*4+r][n=q=lr]
#pragma unroll
  for (int i = 0; i < 4; ++i) o[i] = (f32x4){0.f, 0.f, 0.f, 0.f};
  float lsum = 0.f;

  // staging: K rows srow, srow+64 (same parity -> same swizzle); V rows
  // srow (hd), kv chunks sxv and sxv+64.
  const int srow = tid >> 3;                       // 0..63
  const int sxk  = ((tid & 7) ^ (srow & 7)) << 3;  // K swizzled source chunk
  const int sxv  = (tid & 7) << 3;
  const int kdst = wave * 512;                     // wave-uniform LDS elems

  // frag-read LDS offsets (elems)
  const int koff0 = lr * 64 + ((lq ^ (lr & 7)) << 3);
  const int koff1 = lr * 64 + (((lq + 4) ^ (lr & 7)) << 3);
  const int voff  = lr * VPADA + lq * 4;

  const bf16_t* Kg0 = Kp + tok0 * 1024 + col0;
  const bf16_t* Vg0 = Vt + (size_t)col0 * 4096 + tok0;

  auto stage_k = [&](const bf16_t* Kg, bf16_t* Ksn) {
    async16(Kg + (size_t)srow * 1024 + sxk, Ksn + kdst);
    async16(Kg + (size_t)(srow + 64) * 1024 + sxk, Ksn + kdst + 4096);
  };

  auto compute_tile = [&](const bf16_t* Ksc, const bf16_t* Vsc) {
#pragma unroll
    for (int c = 0; c < 8; ++c) {
      const bf16x8 kf0 = ldg8(&Ksc[c * 1024 + koff0]);
      const bf16x8 kf1 = ldg8(&Ksc[c * 1024 + koff1]);
      f32x4 sT = {0.f, 0.f, 0.f, 0.f};
      sT = MFMA(kf0, qf[0], sT);
      sT = MFMA(kf1, qf[1], sT);
      const float p0 = fast_exp2(sT.x);
      const float p1 = fast_exp2(sT.y);
      const float p2 = fast_exp2(sT.z);
      const float p3 = fast_exp2(sT.w);
      bf16x4 pb;
      pb[0] = (__bf16)p0; pb[1] = (__bf16)p1;
      pb[2] = (__bf16)p2; pb[3] = (__bf16)p3;
      lsum += (p0 + p1) + (p2 + p3);
#pragma unroll
      for (int ht = 0; ht < 4; ++ht) {
        const bf16x4 vf = ldg4(&Vsc[ht * 16 * VPADA + voff + c * 16]);
        o[ht] = mfma16(vf, pb, o[ht]);
      }
    }
  };

  // prologue: stage tile 0 into buffer 0
  {
    const bf16x8 v0 = ldg8(Vg0 + (size_t)srow * 4096 + sxv);
    const bf16x8 v1 = ldg8(Vg0 + (size_t)srow * 4096 + sxv + 64);
    stage_k(Kg0, Ks0);
    st8(&Vs0[srow * VPADA + sxv], v0);
    st8(&Vs0[srow * VPADA + sxv + 64], v1);
  }

#pragma unroll 1
  for (int t = 0; t < 16; t += 2) {
    // --- step A: compute buf0 (tile t), stage tile t+1 into buf1 ---
    __syncthreads();  // buf0 staged; drains prior-iteration asyncs (landed)
    {
      const bf16_t* Kg = Kg0 + (size_t)(t + 1) * 131072;
      const bf16_t* Vg = Vg0 + (t + 1) * 128;
      const bf16x8 v0 = ldg8(Vg + (size_t)srow * 4096 + sxv);
      const bf16x8 v1 = ldg8(Vg + (size_t)srow * 4096 + sxv + 64);
      stage_k(Kg, Ks1);
      compute_tile(Ks0, Vs0);
      st8(&Vs1[srow * VPADA + sxv], v0);
      st8(&Vs1[srow * VPADA + sxv + 64], v1);
    }
    // --- step B: compute buf1 (tile t+1), stage tile t+2 into buf0 ---
    __syncthreads();
    if (t + 2 < 16) {
      const bf16_t* Kg = Kg0 + (size_t)(t + 2) * 131072;
      const bf16_t* Vg = Vg0 + (t + 2) * 128;
      const bf16x8 v0 = ldg8(Vg + (size_t)srow * 4096 + sxv);
      const bf16x8 v1 = ldg8(Vg + (size_t)srow * 4096 + sxv + 64);
      stage_k(Kg, Ks0);
      compute_tile(Ks1, Vs1);
      st8(&Vs0[srow * VPADA + sxv], v0);
      st8(&Vs0[srow * VPADA + sxv + 64], v1);
    } else {
      compute_tile(Ks1, Vs1);
    }
  }

  // make sure all waves are done with Ks/Vs before overlaying scratch
  __syncthreads();

  float* Ow = &Osc[wave * 64 * 17];
  {
    // l: per-lane partial over kv ≡ lq quadrant; reduce across lq
    float ls = lsum;
    ls += __shfl_xor(ls, 16);
    ls += __shfl_xor(ls, 32);
    const float invl = 1.f / ls;

    // wave-private transpose bounce (in-wave DS ordering, no barrier)
#pragma unroll
    for (int ht = 0; ht < 4; ++ht)
#pragma unroll
      for (int r = 0; r < 4; ++r)
        Ow[(ht * 16 + lq * 4 + r) * 17 + lr] = o[ht][r] * invl;

    const int qq = lane >> 2;          // 0..15
    const int hc = (lane & 3) * 16;    // hd segment
    bf16x8 w0, w1;
#pragma unroll
    for (int i = 0; i < 8; ++i) {
      w0[i] = (__bf16)Ow[(hc + i) * 17 + qq];
      w1[i] = (__bf16)Ow[(hc + 8 + i) * 17 + qq];
    }
    bf16_t* dst = Ao + (tok0 + qblk + qq) * 1024 + col0 + hc;
    st8(dst, w0);
    st8(dst + 8, w1);
  }
}

extern "C" void kernel_launch(void* const* d_in, const int* in_sizes, int n_in,
                              void* d_out, int out_size, void* d_ws, size_t ws_size,
                              hipStream_t stream) {
  const float* x  = (const float*)d_in[0];
  const float* Wq = (const float*)d_in[1];
  const float* Wk = (const float*)d_in[2];
  const float* Wv = (const float*)d_in[3];
  const float* Wo = (const float*)d_in[4];
  const float* bo = (const float*)d_in[5];
  float* out = (float*)d_out;

  const size_t NTOK = 4096, DMODEL = 1024, WSZ = DMODEL * DMODEL;
  bf16_t* xb  = (bf16_t*)d_ws;
  bf16_t* Wqb = xb + NTOK * DMODEL;
  bf16_t* Wkb = Wqb + WSZ;
  bf16_t* Wvb = Wkb + WSZ;
  bf16_t* Wob = Wvb + WSZ;
  bf16_t* Q   = Wob + WSZ;
  bf16_t* Kp  = Q  + NTOK * DMODEL;
  bf16_t* Vt  = Kp + NTOK * DMODEL;            // [1024][4096] = V^T
  bf16_t* Ao  = Vt + NTOK * DMODEL;

  cvt_kernel<<<dim3(4096), 256, 0, stream>>>(x, Wq, Wk, Wv, Wo, xb, Wqb, Wkb, Wvb, Wob);
  qkv_kernel<<<dim3(256, 3), 256, 0, stream>>>(xb, Wqb, Wkb, Wvb, Q, Kp, Vt);
  attn_kernel<<<dim3(32, 16), 512, 0, stream>>>(Q, Kp, Vt, Ao);
  out_proj_kernel<<<dim3(512, 1), 256, 0, stream>>>(Ao, Wob, bo, out);
}